// Round 1
// baseline (817.771 us; speedup 1.0000x reference)
//
#include <hip/hip_runtime.h>

typedef __bf16 bf16x8 __attribute__((ext_vector_type(8)));
typedef float floatx4 __attribute__((ext_vector_type(4)));

__device__ __forceinline__ float sigmoidf_(float v) {
    return 1.0f / (1.0f + __expf(-v));
}

// smem layout (floats):
// [0,4096)      G        (C..E)  | rowsum [0,2048) + colsum [2048,4096) (A..B)
// [4096,8192)   T1       (C..E)  | astage [4096,6144) (A)
// [8192,10240)  sh       (B..C)  | stats scratch (D)
// [10240,12288) sw       (B..C)
// [12288,16512) ring: 4 slots x 66 w x 32 ci bf16 (4224 B/slot)
// [16512,17568) zrow: 66 x 32 bf16, all zero
// [17568..)     misc: x21, x11, a1, a0, b3c, corners[4][32], Stot, meanx2
extern "C" __global__ __launch_bounds__(256, 2)
void ema_fused(const float* __restrict__ x, const float* __restrict__ w1,
               const float* __restrict__ b1, const float* __restrict__ w3,
               const float* __restrict__ b3, const float* __restrict__ gamma,
               const float* __restrict__ beta, float* __restrict__ out)
{
    __shared__ float sm[17952];
    const int t = threadIdx.x;
    const int b = blockIdx.x;
    const float* gx = x + (size_t)b * 131072;
    float* gout = out + (size_t)b * 131072;

    const int c = t & 31;        // channel owned by this thread (phases A/C/E)
    const int k = t >> 5;        // w-group 0..7
    const int lane = t & 63;
    const int wave = t >> 6;

    float* G      = sm;
    float* T1     = sm + 4096;
    float* rowsum = sm;          // union with G
    float* colsum = sm + 2048;
    float* astage = sm + 4096;   // union with T1, [8][8][32]
    float* shl    = sm + 8192;
    float* swl    = sm + 10240;
    __bf16* ringbase = (__bf16*)(sm + 12288);   // slot s at ringbase + s*2112
    __bf16* zrow     = (__bf16*)(sm + 16512);   // 2112 bf16, zero
    float* x21    = sm + 17568;
    float* x11    = sm + 17600;
    float* a1     = sm + 17632;
    float* a0     = sm + 17664;
    float* b3c    = sm + 17696;
    float* corners= sm + 17728;  // [4][32]: gx[0][0], gx[0][63], gx[63][0], gx[63][63]
    float* Stot   = sm + 17856;
    float* meanx2 = sm + 17888;

    // ---------------- Phase A: rowsum / colsum / corners ----------------
    float colacc[8];
#pragma unroll
    for (int i = 0; i < 8; ++i) colacc[i] = 0.f;

    for (int h8 = 0; h8 < 8; ++h8) {
#pragma unroll
        for (int j = 0; j < 8; ++j) {
            int h = h8 * 8 + j;
            float part = 0.f;
#pragma unroll
            for (int i = 0; i < 8; ++i) {
                int w = k + 8 * i;
                float v = gx[(h * 64 + w) * 32 + c];
                colacc[i] += v;
                part += v;
                if ((h == 0 || h == 63) && w == 0)
                    corners[((h == 63) ? 2 : 0) * 32 + c] = v;
                if ((h == 0 || h == 63) && w == 63)
                    corners[((h == 63) ? 3 : 1) * 32 + c] = v;
            }
            astage[(j * 8 + k) * 32 + c] = part;
        }
        __syncthreads();
        {   // reduce 8 rows: each thread one (j,c)
            int j2 = t >> 5, c2 = t & 31;
            float s = 0.f;
#pragma unroll
            for (int k2 = 0; k2 < 8; ++k2) s += astage[(j2 * 8 + k2) * 32 + c2];
            rowsum[(h8 * 8 + j2) * 32 + c2] = s;
        }
        __syncthreads();
    }
#pragma unroll
    for (int i = 0; i < 8; ++i) colsum[(k + 8 * i) * 32 + c] = colacc[i];
    __syncthreads();

    // ---------------- Phase B: sh, sw, mean_x2 (analytic), x21, x11 ----------------
    {
        int hh = t >> 2;
        int d0 = (t & 3) * 8;
#pragma unroll
        for (int kk = 0; kk < 8; ++kk) {
            int d = d0 + kk;
            float acch = b1[d], accw = b1[d];
            for (int ci = 0; ci < 32; ++ci) {
                float wv = w1[ci * 32 + d];
                acch += rowsum[hh * 32 + ci] * (1.f / 64.f) * wv;
                accw += colsum[hh * 32 + ci] * (1.f / 64.f) * wv;
            }
            shl[hh * 32 + d] = sigmoidf_(acch);
            swl[hh * 32 + d] = sigmoidf_(accw);
        }
    }
    if (t < 32) {
        float s = 0.f;
        for (int h = 0; h < 64; ++h) s += rowsum[h * 32 + t];
        Stot[t] = s;
        b3c[t] = b3[t];
    }
    __syncthreads();
    if (t < 32) {   // mean of conv output per co, from window sums
        int co = t;
        float acc = 0.f;
        for (int dh = -1; dh <= 1; ++dh)
            for (int dw = -1; dw <= 1; ++dw) {
                int ks = (dh + 1) * 3 + (dw + 1);
                for (int ci = 0; ci < 32; ++ci) {
                    float S = Stot[ci];
                    if (dh == -1) S -= rowsum[63 * 32 + ci];
                    if (dh ==  1) S -= rowsum[ci];
                    if (dw == -1) S -= colsum[63 * 32 + ci];
                    if (dw ==  1) S -= colsum[ci];
                    if (dh == -1 && dw == -1) S += corners[3 * 32 + ci]; // gx[63][63]
                    if (dh == -1 && dw ==  1) S += corners[2 * 32 + ci]; // gx[63][0]
                    if (dh ==  1 && dw == -1) S += corners[1 * 32 + ci]; // gx[0][63]
                    if (dh ==  1 && dw ==  1) S += corners[0 * 32 + ci]; // gx[0][0]
                    acc += w3[ks * 1024 + ci * 32 + co] * S;
                }
            }
        meanx2[co] = acc * (1.f / 4096.f) + b3[co];
    }
    __syncthreads();
    if (t == 0) {   // x21 = softmax(mean_x2)
        float m = meanx2[0];
        for (int i = 1; i < 32; ++i) m = fmaxf(m, meanx2[i]);
        float s = 0.f;
        for (int i = 0; i < 32; ++i) { float e = __expf(meanx2[i] - m); x21[i] = e; s += e; }
        float inv = 1.f / s;
        for (int i = 0; i < 32; ++i) x21[i] *= inv;
    } else if (t == 64) {   // x11 = softmax(beta)  (mean(x1) == beta analytically)
        float m = -1e30f;
        for (int i = 0; i < 32; ++i) m = fmaxf(m, beta[i]);
        float s = 0.f;
        for (int i = 0; i < 32; ++i) s += __expf(beta[i] - m);
        float inv = 1.f / s;
        for (int i = 0; i < 32; ++i) x11[i] = __expf(beta[i] - m) * inv;
    }
    __syncthreads();

    // ---------------- B-fragments for conv (resident in VGPRs) ----------------
    bf16x8 Bf[9][2];
    {
        int ci0 = (lane >> 4) * 8;
        int co  = lane & 15;
#pragma unroll
        for (int ks = 0; ks < 9; ++ks)
#pragma unroll
            for (int nf = 0; nf < 2; ++nf) {
                bf16x8 v;
#pragma unroll
                for (int j = 0; j < 8; ++j)
                    v[j] = (__bf16)w3[ks * 1024 + (ci0 + j) * 32 + nf * 16 + co];
                Bf[ks][nf] = v;
            }
    }

    // ---------------- Phase C init: zero G/T1, zrow, ring halos ----------------
    for (int i = t; i < 8192; i += 256) sm[i] = 0.f;      // G + T1
    for (int i = t; i < 1056; i += 256) sm[16512 + i] = 0.f;  // zrow
    {
        int s = t >> 6, colsel = (t >> 5) & 1, cc = t & 31;
        ringbase[s * 2112 + (colsel ? 65 * 32 : 0) + cc] = (__bf16)0.f;
    }
    __syncthreads();

    // ---------------- Phase C: stream rows; gated+G+stats and MFMA conv+T1 ----------------
    float sumg = 0.f, sumg2 = 0.f;
    auto stage = [&](int r) {
        __bf16* rowp = ringbase + (r & 3) * 2112;
        float coef = x21[r >> 1];
        int par = (r & 1) << 11;
#pragma unroll
        for (int i = 0; i < 8; ++i) {
            int w = k + 8 * i;
            float v = gx[(r * 64 + w) * 32 + c];
            rowp[(w + 1) * 32 + c] = (__bf16)v;
            float g = v * shl[r * 32 + c] * swl[w * 32 + c];
            sumg += g; sumg2 += g * g;
            G[par + w * 32 + c] += coef * g;
        }
    };
    stage(0);

    const int wbase = wave * 16;
    const int m_ = lane & 15;
    const int q_ = lane >> 4;
    for (int h = 0; h < 64; ++h) {
        if (h < 63) stage(h + 1);
        __syncthreads();
        floatx4 acc0 = {0.f, 0.f, 0.f, 0.f}, acc1 = {0.f, 0.f, 0.f, 0.f};
#pragma unroll
        for (int dh = -1; dh <= 1; ++dh) {
            int r = h + dh;
            const __bf16* rowp = (r < 0 || r > 63) ? zrow : (ringbase + (r & 3) * 2112);
#pragma unroll
            for (int dw = -1; dw <= 1; ++dw) {
                int ks = (dh + 1) * 3 + (dw + 1);
                const __bf16* ap = rowp + (wbase + m_ + dw + 1) * 32 + q_ * 8;
                bf16x8 av = *(const bf16x8*)ap;   // ds_read_b128
                acc0 = __builtin_amdgcn_mfma_f32_16x16x32_bf16(av, Bf[ks][0], acc0, 0, 0, 0);
                acc1 = __builtin_amdgcn_mfma_f32_16x16x32_bf16(av, Bf[ks][1], acc1, 0, 0, 0);
            }
        }
        {   // T1 += x11[h>>1] * conv_row   (C layout: row=(q*4+reg), col=lane&15)
            float coef = x11[h >> 1];
            int par = (h & 1) << 11;
#pragma unroll
            for (int rr = 0; rr < 4; ++rr) {
                int w = wbase + q_ * 4 + rr;
                int idx = par + w * 32 + (lane & 15);
                T1[idx]      += coef * acc0[rr];
                T1[idx + 16] += coef * acc1[rr];
            }
        }
    }
    __syncthreads();

    // ---------------- Phase D: group stats -> a1, a0 ----------------
    shl[k * 32 + c] = sumg;          // reuse sh area as scratch
    shl[256 + k * 32 + c] = sumg2;
    __syncthreads();
    if (t < 32) {
        float S = 0.f, S2 = 0.f;
        for (int kk = 0; kk < 8; ++kk) { S += shl[kk * 32 + t]; S2 += shl[256 + kk * 32 + t]; }
        float mu  = S * (1.f / 4096.f);
        float var = S2 * (1.f / 4096.f) - mu * mu;
        float rs  = rsqrtf(var + 0.001f);
        float g1  = gamma[t] * rs;
        a1[t] = g1;
        a0[t] = beta[t] - g1 * mu;
    }
    __syncthreads();

    // ---------------- Phase E: out = gx * sigmoid(weights) ----------------
    for (int h = 0; h < 64; ++h) {
#pragma unroll
        for (int i = 0; i < 8; ++i) {
            int w = k + 8 * i;
            int l = h * 64 + w;
            int cp = w & 31;
            float wt = T1[l] + b3c[cp] + a1[cp] * G[l] + a0[cp];
            float sg = sigmoidf_(wt);
            gout[(h * 64 + w) * 32 + c] = gx[(h * 64 + w) * 32 + c] * sg;
        }
    }
}

extern "C" void kernel_launch(void* const* d_in, const int* in_sizes, int n_in,
                              void* d_out, int out_size, void* d_ws, size_t ws_size,
                              hipStream_t stream) {
    const float* x  = (const float*)d_in[0];
    const float* w1 = (const float*)d_in[1];
    const float* b1 = (const float*)d_in[2];
    const float* w3 = (const float*)d_in[3];
    const float* b3 = (const float*)d_in[4];
    const float* gg = (const float*)d_in[5];
    const float* gb = (const float*)d_in[6];
    float* out = (float*)d_out;
    hipLaunchKernelGGL(ema_fused, dim3(512), dim3(256), 0, stream,
                       x, w1, b1, w3, b3, gg, gb, out);
}